// Round 9
// baseline (4707.060 us; speedup 1.0000x reference)
//
#include <hip/hip_runtime.h>
#include <math.h>

// Problem constants (fixed by setup_inputs)
#define NN   256   // nodes
#define HH   450   // hidden
#define LATD 56    // latent
#define VV   780   // vocab
#define LL   511   // path length (2N-1)
#define GSEQ 32    // persistent blocks
#define TSEQ 512   // threads per persistent block
#define KMAX 15    // max rows per block (450 = 15+15+14*30)
#define LMD  64    // max in-deps per message
#define MAXLEV 600

__device__ __forceinline__ float wred_sum(float v) {
    for (int off = 32; off; off >>= 1) v += __shfl_down(v, off, 64);
    return v;
}
__device__ __forceinline__ void aaddf(float* p, float v) {
    (void)__hip_atomic_fetch_add(p, v, __ATOMIC_RELAXED, __HIP_MEMORY_SCOPE_AGENT);
}

// ---- fenced all-poll grid barrier (round-2 pattern: empirically correct) ----
// Plain cached loads/stores between barriers are made coherent by the
// release (wb L2->L3) / acquire (inv L1,L2) fences around the flag exchange.
__device__ __forceinline__ void gridbar(unsigned* slots, unsigned ph) {
    __syncthreads();   // all block stores drained (vmcnt) before fence
    const int tid = threadIdx.x;
    if (tid == 0) {
        __threadfence();   // release: write back dirty L2
        __hip_atomic_store(&slots[blockIdx.x * 16], ph,
                           __ATOMIC_RELAXED, __HIP_MEMORY_SCOPE_AGENT);
    }
    if (tid < GSEQ) {
        while (__hip_atomic_load(&slots[tid * 16],
                                 __ATOMIC_RELAXED, __HIP_MEMORY_SCOPE_AGENT) < ph) {
            __builtin_amdgcn_s_sleep(1);
        }
        __threadfence();   // acquire: invalidate stale L1/L2 lines (per-CU/XCD)
    }
    __syncthreads();
}

// ---- find vocab id of each node's one-hot feature ----
__global__ void k_vid(const float* __restrict__ nf, int* __restrict__ vid) {
    const int u = blockIdx.x;
    for (int v = threadIdx.x; v < VV; v += blockDim.x)
        if (nf[(size_t)u * VV + v] > 0.5f) vid[u] = v;
}

// ---- per-node constants: cz, r1, sigma(r1), ch, and Ud . relu(d12) scalar ----
__global__ __launch_bounds__(512) void k_consts(
    const int* __restrict__ vid, const float* __restrict__ latent,
    const float* __restrict__ Wz, const float* __restrict__ Wzb,
    const float* __restrict__ Wr, const float* __restrict__ Wrb,
    const float* __restrict__ Wh, const float* __restrict__ Whb,
    const float* __restrict__ Wd12, const float* __restrict__ Wd12b,
    const float* __restrict__ Ud,
    float* __restrict__ cz, float* __restrict__ r1s, float* __restrict__ sig0,
    float* __restrict__ ch, float* __restrict__ dotd12)
{
    const int u = blockIdx.x, tid = threadIdx.x;
    const int v = vid[u];
    __shared__ float red[8];
    float p = 0.f;
    if (tid < HH) {
        const int i = tid, o = u * HH + i;
        cz[o] = Wz[(size_t)i * (VV + HH) + v] + Wzb[i];
        const float r1 = Wr[(size_t)i * VV + v] + Wrb[i];
        r1s[o] = r1;
        sig0[o] = 1.f / (1.f + expf(-r1));
        ch[o] = Wh[(size_t)i * (VV + HH) + v] + Whb[i];
        float d = Wd12[(size_t)i * (VV + LATD) + v] + Wd12b[i];
        for (int k = 0; k < LATD; ++k)
            d += Wd12[(size_t)i * (VV + LATD) + VV + k] * latent[k];
        p = Ud[i] * fmaxf(d, 0.f);
    }
    p = wred_sum(p);
    if ((tid & 63) == 0) red[tid >> 6] = p;
    __syncthreads();
    if (tid == 0) {
        float s = 0.f;
        for (int w = 0; w < 8; ++w) s += red[w];
        dotd12[u] = s;
    }
}

// ---- WhSig0[u] = Wh_H @ sigma(r1[u]) ----
__global__ __launch_bounds__(512) void k_whsig0(
    const float* __restrict__ Wh, const float* __restrict__ sig0, float* __restrict__ out)
{
    const int u = blockIdx.x, tid = threadIdx.x, wave = tid >> 6, lane = tid & 63;
    __shared__ float sg[HH];
    if (tid < HH) sg[tid] = sig0[u * HH + tid];
    __syncthreads();
    for (int r = wave; r < HH; r += 8) {
        float acc = 0.f;
        for (int k = lane; k < HH; k += 64)
            acc += Wh[(size_t)r * (VV + HH) + VV + k] * sg[k];
        acc = wred_sum(acc);
        if (lane == 0) out[u * HH + r] = acc;
    }
}

// ---- per-step exclusion index + precomputed neighbor-count coefficient ----
__global__ void k_excl(const int* __restrict__ node_ids, const int* __restrict__ next_ids,
                       int* __restrict__ excl, float* __restrict__ ccpre)
{
    const int t = blockIdx.x;
    __shared__ int ex, cnt;
    if (threadIdx.x == 0) { ex = -1; cnt = 0; }
    __syncthreads();
    const int a = node_ids[t], b = next_ids[t];
    for (int tp = threadIdx.x; tp <= t; tp += blockDim.x) {
        if (tp < t && node_ids[tp] == b && next_ids[tp] == a) ex = tp;
        if (tp >= 1 && node_ids[tp] == a) atomicAdd(&cnt, 1);
    }
    __syncthreads();
    if (threadIdx.x == 0) {
        excl[t] = ex;
        ccpre[t] = 256.f - (float)cnt + (ex >= 0 ? 1.f : 0.f);
    }
}

// ---- prep: dep-lists, DAG levels, level buckets (single block) ----
// zlist[t] = {tp < t : next_ids[tp]==node_ids[t], tp != excl[t]}  (in-msgs, masked)
// lev[t] = 1 + max(lev[dep]) over zlist[t] U {excl[t]}; bucket by level.
__global__ __launch_bounds__(512) void k_prep(
    const int* __restrict__ node_ids, const int* __restrict__ next_ids,
    const int* __restrict__ excl,
    int* __restrict__ zlist, int* __restrict__ zcnt,
    int* __restrict__ order, int* __restrict__ levStart, int* __restrict__ nLevOut)
{
    const int tid = threadIdx.x, lane = tid & 63;
    __shared__ int levS[LL];
    __shared__ int cnts[MAXLEV];
    __shared__ int nLevS;
    // Phase A: dep lists (thread per t, ordered scan -> deterministic)
    for (int t = tid; t < LL; t += 512) {
        const int a = node_ids[t], e = excl[t];
        int c = 0;
        for (int tp = 0; tp < t; ++tp)
            if (next_ids[tp] == a && tp != e) zlist[t * LMD + c++] = tp;
        zcnt[t] = c;
    }
    for (int i = tid; i < MAXLEV; i += 512) cnts[i] = 0;
    __syncthreads();
    // Phase B: sequential leveling by wave 0
    if (tid < 64) {
        for (int t = 0; t < LL; ++t) {
            int mx = 0;
            const int zc = zcnt[t];
            for (int i = lane; i < zc; i += 64) {
                const int j = zlist[t * LMD + i];
                mx = max(mx, levS[j]);
            }
            if (lane == 0) { const int e = excl[t]; if (e >= 0) mx = max(mx, levS[e]); }
            for (int off = 32; off; off >>= 1) mx = max(mx, __shfl_down(mx, off, 64));
            mx = __shfl(mx, 0, 64);       // broadcast
            if (lane == 0) levS[t] = mx + 1;
            __builtin_amdgcn_s_waitcnt(0); // lgkmcnt drain: write visible to wave
        }
    }
    __syncthreads();
    // Phase C: stable bucket by thread 0
    if (tid == 0) {
        int nl = 0;
        for (int t = 0; t < LL; ++t) { cnts[levS[t]]++; nl = max(nl, levS[t]); }
        int run = 0;
        for (int k = 1; k <= nl; ++k) { levStart[k] = run; run += cnts[k]; cnts[k] = 0; }
        levStart[nl + 1] = LL;
        for (int t = 0; t < LL; ++t) {
            const int k = levS[t];
            order[levStart[k] + cnts[k]] = t;
            cnts[k]++;
        }
        *nLevOut = nl;
        nLevS = nl;
    }
    __syncthreads(); (void)nLevS;
}

// ---- copy stops/real_labels into d_out; zero the pred_stop region ----
__global__ void k_copy(const int* __restrict__ stops, const int* __restrict__ reall,
                       float* __restrict__ out)
{
    const int i = blockIdx.x * blockDim.x + threadIdx.x;
    if (i < LL) { out[i] = (float)stops[i]; out[LL + i] = 0.f; }
    if (i < NN) out[2 * LL + i] = (float)reall[i];
}

// ---- level-batched scan: 2 fence-barriers per DAG level (~70 total) ----
// Row-partition: block b owns rows R_b of every vector; 4 weight-row slices
// in registers. Phase 1 (per message in level): gather dep transforms (plain
// cached reads), sigma-sum + elementwise + Wh matvec -> nh rows; pred_stop
// partial via fire-and-forget atomic. Phase 2: Ur/Wz/Wd3 transforms of the
// level's new messages. All cross-block state is plain memory fenced by the
// level barriers.
__global__ __launch_bounds__(TSEQ) void k_seq(
    const int* __restrict__ node_ids,
    const int* __restrict__ excl, const float* __restrict__ ccpre,
    const int* __restrict__ zlist, const int* __restrict__ zcnt,
    const int* __restrict__ order, const int* __restrict__ levStart,
    const int* __restrict__ nLevPtr,
    const float* __restrict__ Ur, const float* __restrict__ Wz,
    const float* __restrict__ Wh, const float* __restrict__ Wd3,
    const float* __restrict__ Wd3b, const float* __restrict__ Ud,
    const float* __restrict__ Udb,
    const float* __restrict__ cz, const float* __restrict__ r1s,
    const float* __restrict__ ch, const float* __restrict__ WhSig0,
    const float* __restrict__ dotd12,
    float* __restrict__ NewH, float* __restrict__ UrMv,
    float* __restrict__ WzMv, float* __restrict__ Wd3Mv,
    float* __restrict__ pred_out, unsigned* __restrict__ bar)
{
    const int tid = threadIdx.x, bid = blockIdx.x;
    const int wave = tid >> 6, lane = tid & 63;
    const int kcnt = 14 + (bid < 2 ? 1 : 0);
    const int kbeg = 14 * bid + (bid < 2 ? bid : 2);

    __shared__ float sig_s[512];
    __shared__ float nh_s[512];
    __shared__ float zargS[KMAX], svS[KMAX];

    // Row slices of Ur / Wz_H / Wh_H / Wd3 in registers (zero-padded)
    float ur_r[2][8], wz_r[2][8], wh_r[2][8], wd3_r[2][8];
    for (int it = 0; it < 2; ++it) {
        const int j = wave + 8 * it;
        const bool vj = j < kcnt;
        const int row = vj ? (kbeg + j) : 0;
        for (int e = 0; e < 8; ++e) {
            const int c = lane + 64 * e;
            const bool v = vj && (c < HH);
            ur_r[it][e]  = v ? Ur[(size_t)row * HH + c] : 0.f;
            wz_r[it][e]  = v ? Wz[(size_t)row * (VV + HH) + VV + c] : 0.f;
            wh_r[it][e]  = v ? Wh[(size_t)row * (VV + HH) + VV + c] : 0.f;
            wd3_r[it][e] = v ? Wd3[(size_t)row * HH + c] : 0.f;
        }
    }
    if (tid >= HH) { sig_s[tid] = 0.f; nh_s[tid] = 0.f; }  // zero pad once

    const int nLev = *nLevPtr;
    unsigned ph = 0;
    __syncthreads();

    for (int lev = 1; lev <= nLev; ++lev) {
        const int m0 = levStart[lev], m1 = levStart[lev + 1];
        // ---- phase 1: nh for every message in this level ----
        for (int m = m0; m < m1; ++m) {
            const int t = order[m];
            const int a = node_ids[t];
            const int zc = zcnt[t];
            const int ex = excl[t];
            const float cc = ccpre[t];
            // sigma-sum over deps (elementwise, all 450 rows)
            if (tid < HH) {
                float ss = 0.f;
                for (int i = 0; i < zc; ++i) {
                    const int j = zlist[t * LMD + i];
                    const float u = r1s[a * HH + tid] + UrMv[(size_t)j * HH + tid];
                    ss += 1.f / (1.f + expf(-u));
                }
                sig_s[tid] = ss;
            }
            // own-row elementwise sums + pred_stop partial
            float ps = 0.f;
            if (tid < kcnt) {
                const int r = kbeg + tid;
                float zarg = cz[a * HH + r];
                float sv = 0.f, d3 = 0.f;
                for (int i = 0; i < zc; ++i) {
                    const int j = zlist[t * LMD + i];
                    zarg += WzMv[(size_t)j * HH + r];
                    sv   += NewH[(size_t)j * HH + r];
                    d3   += Wd3Mv[(size_t)j * HH + r];
                }
                if (ex >= 0) d3 += Wd3Mv[(size_t)ex * HH + r];
                zargS[tid] = zarg;
                svS[tid] = sv;
                ps = Ud[HH + r] * fmaxf(d3 + Wd3b[r], 0.f);
            }
            if (wave == 0) {   // pred partial lives entirely in wave 0
                ps = wred_sum(ps);
                if (lane == 0) {
                    if (bid == 0) ps += dotd12[a] + Udb[0];
                    aaddf(&pred_out[t], ps);
                }
            }
            __syncthreads();
            // whv matvec + nh for own rows
            for (int it = 0; it < 2; ++it) {
                const int j = wave + 8 * it;
                float acc = 0.f;
                if (zc > 0) {
                    #pragma unroll
                    for (int e = 0; e < 8; ++e) acc += wh_r[it][e] * sig_s[lane + 64 * e];
                    acc = wred_sum(acc);
                }
                if (lane == 0 && j < kcnt) {
                    const int r = kbeg + j;
                    const float whv = acc + ch[a * HH + r] + cc * WhSig0[a * HH + r];
                    const float z = 1.f / (1.f + expf(-zargS[j]));
                    NewH[(size_t)t * HH + r] = (1.f - z) * svS[j] + z * tanhf(whv);
                }
            }
            __syncthreads();
        }
        gridbar(bar, ++ph);   // nh of this level visible everywhere

        // ---- phase 2: transforms of this level's messages ----
        for (int m = m0; m < m1; ++m) {
            const int t = order[m];
            if (tid < HH) nh_s[tid] = NewH[(size_t)t * HH + tid];
            __syncthreads();
            for (int it = 0; it < 2; ++it) {
                const int j = wave + 8 * it;
                float au = 0.f, az = 0.f, ad = 0.f;
                #pragma unroll
                for (int e = 0; e < 8; ++e) {
                    const float nv = nh_s[lane + 64 * e];
                    au += ur_r[it][e]  * nv;
                    az += wz_r[it][e]  * nv;
                    ad += wd3_r[it][e] * nv;
                }
                au = wred_sum(au); az = wred_sum(az); ad = wred_sum(ad);
                if (lane == 0 && j < kcnt) {
                    const int r = kbeg + j;
                    UrMv[(size_t)t * HH + r]  = au;
                    WzMv[(size_t)t * HH + r]  = az;
                    Wd3Mv[(size_t)t * HH + r] = ad;
                }
            }
            __syncthreads();
        }
        gridbar(bar, ++ph);   // transforms visible before next level
    }
}

// ---- labels: root (q=0, outer relu, no softmax) + 255 label steps (softmax) ----
__global__ __launch_bounds__(512) void k_label(
    const float* __restrict__ latent, const int* __restrict__ lsteps,
    const float* __restrict__ NewH,
    const float* __restrict__ Wl, const float* __restrict__ Wlb,
    const float* __restrict__ Ul, const float* __restrict__ Ulb,
    float* __restrict__ out)
{
    const int q = blockIdx.x, tid = threadIdx.x, wave = tid >> 6, lane = tid & 63;
    __shared__ float inp[LATD + HH];
    __shared__ float t2[HH];
    __shared__ float lg[VV];
    __shared__ float red[8];
    if (tid < LATD) inp[tid] = latent[tid];
    if (q == 0) {
        if (tid < HH) inp[LATD + tid] = 0.f;
    } else {
        const int t = lsteps[q - 1];
        if (tid < HH) inp[LATD + tid] = NewH[(size_t)t * HH + tid];
    }
    __syncthreads();
    for (int r = wave; r < HH; r += 8) {
        float acc = 0.f;
        for (int k = lane; k < LATD + HH; k += 64)
            acc += Wl[(size_t)r * (LATD + HH) + k] * inp[k];
        acc = wred_sum(acc);
        if (lane == 0) {
            const float v = acc + Wlb[r];
            t2[r] = (q == 0) ? v : fmaxf(v, 0.f);   // root: no inner relu
        }
    }
    __syncthreads();
    for (int r = wave; r < VV; r += 8) {
        float acc = 0.f;
        for (int k = lane; k < HH; k += 64) acc += Ul[(size_t)r * HH + k] * t2[k];
        acc = wred_sum(acc);
        if (lane == 0) lg[r] = acc + Ulb[r];
    }
    __syncthreads();
    float* outrow = out + 2 * LL + NN + (size_t)q * VV;
    if (q == 0) {   // root: relu, no softmax
        for (int i = tid; i < VV; i += 512) outrow[i] = fmaxf(lg[i], 0.f);
        return;
    }
    float mx = -1e30f;
    for (int i = tid; i < VV; i += 512) mx = fmaxf(mx, lg[i]);
    for (int off = 32; off; off >>= 1) mx = fmaxf(mx, __shfl_down(mx, off, 64));
    if (lane == 0) red[wave] = mx;
    __syncthreads();
    if (tid == 0) {
        float m = red[0];
        for (int w = 1; w < 8; ++w) m = fmaxf(m, red[w]);
        red[0] = m;
    }
    __syncthreads();
    const float M = red[0];
    float sum = 0.f;
    for (int i = tid; i < VV; i += 512) { const float e = expf(lg[i] - M); lg[i] = e; sum += e; }
    __syncthreads();
    sum = wred_sum(sum);
    if (lane == 0) red[wave] = sum;
    __syncthreads();
    if (tid == 0) {
        float s = 0.f;
        for (int w = 0; w < 8; ++w) s += red[w];
        red[0] = s;
    }
    __syncthreads();
    const float S = red[0];
    for (int i = tid; i < VV; i += 512) outrow[i] = lg[i] / S;
}

extern "C" void kernel_launch(void* const* d_in, const int* in_sizes, int n_in,
                              void* d_out, int out_size, void* d_ws, size_t ws_size,
                              hipStream_t stream)
{
    const float* latent = (const float*)d_in[0];
    const float* nodef  = (const float*)d_in[1];
    const int* node_ids = (const int*)d_in[2];
    const int* next_ids = (const int*)d_in[3];
    const int* stops    = (const int*)d_in[4];
    const int* lsteps   = (const int*)d_in[5];
    const int* reall    = (const int*)d_in[6];
    const float* Wz   = (const float*)d_in[7];
    const float* Wzb  = (const float*)d_in[8];
    const float* Urw  = (const float*)d_in[9];
    const float* Wr   = (const float*)d_in[10];
    const float* Wrb  = (const float*)d_in[11];
    const float* Wh   = (const float*)d_in[12];
    const float* Whb  = (const float*)d_in[13];
    const float* Wd12 = (const float*)d_in[14];
    const float* Wd12b= (const float*)d_in[15];
    const float* Wd3  = (const float*)d_in[16];
    const float* Wd3b = (const float*)d_in[17];
    const float* Ud   = (const float*)d_in[18];
    const float* Udb  = (const float*)d_in[19];
    const float* Wl   = (const float*)d_in[20];
    const float* Wlb  = (const float*)d_in[21];
    const float* Ul   = (const float*)d_in[22];
    const float* Ulb  = (const float*)d_in[23];
    (void)in_sizes; (void)n_in; (void)out_size; (void)ws_size;
    float* out = (float*)d_out;
    float* W = (float*)d_ws;

    size_t o = 0;
    unsigned* bar = (unsigned*)(W + o); o += GSEQ * 16;
    const size_t zero_floats = o;           // barrier slots must start at 0
    int*   vid    = (int*)(W + o); o += NN;
    int*   excl   = (int*)(W + o); o += LL + 1;
    float* ccpre  = W + o; o += LL + 1;
    int*   zlist  = (int*)(W + o); o += (size_t)LL * LMD;
    int*   zcnt   = (int*)(W + o); o += LL;
    int*   order  = (int*)(W + o); o += LL;
    int*   levSt  = (int*)(W + o); o += MAXLEV + 2;
    int*   nLev   = (int*)(W + o); o += 4;
    float* cz     = W + o; o += NN * HH;
    float* r1s    = W + o; o += NN * HH;
    float* sig0   = W + o; o += NN * HH;
    float* ch     = W + o; o += NN * HH;
    float* WhSig0 = W + o; o += NN * HH;
    float* dotd12 = W + o; o += NN;
    float* NewH   = W + o; o += (size_t)LL * HH;
    float* UrMv   = W + o; o += (size_t)LL * HH;
    float* WzMv   = W + o; o += (size_t)LL * HH;
    float* Wd3Mv  = W + o; o += (size_t)LL * HH;

    hipMemsetAsync(W, 0, zero_floats * sizeof(float), stream);
    k_vid   <<<NN, 256, 0, stream>>>(nodef, vid);
    k_consts<<<NN, 512, 0, stream>>>(vid, latent, Wz, Wzb, Wr, Wrb, Wh, Whb,
                                     Wd12, Wd12b, Ud, cz, r1s, sig0, ch, dotd12);
    k_whsig0<<<NN, 512, 0, stream>>>(Wh, sig0, WhSig0);
    k_excl  <<<LL, 256, 0, stream>>>(node_ids, next_ids, excl, ccpre);
    k_prep  <<<1, 512, 0, stream>>>(node_ids, next_ids, excl,
                                    zlist, zcnt, order, levSt, nLev);
    k_copy  <<<2, 256, 0, stream>>>(stops, reall, out);
    k_seq   <<<GSEQ, TSEQ, 0, stream>>>(node_ids, excl, ccpre,
                                        zlist, zcnt, order, levSt, nLev,
                                        Urw, Wz, Wh, Wd3, Wd3b, Ud, Udb,
                                        cz, r1s, ch, WhSig0, dotd12,
                                        NewH, UrMv, WzMv, Wd3Mv,
                                        out + LL, bar);
    k_label <<<NN, 512, 0, stream>>>(latent, lsteps, NewH, Wl, Wlb, Ul, Ulb, out);
}